// Round 10
// baseline (1885.445 us; speedup 1.0000x reference)
//
#include <hip/hip_runtime.h>
#include <math.h>

#define HH 4096
#define WW 4096
#define NB 8            // blocks; each owns 512 rows (8 waves x 64 lanes)
#define BT 512
#define U 8
#define NGR (WW / U)    // 512 groups of 8 columns
#define RING_E 512      // LDS halo ring: 512 entries (64 groups) per boundary
#define RMASK (RING_E - 1)
#define GATE 64         // inter-block gate (global halo lead, cols)
#define LGATE 32        // intra-block inter-wave gate (cols)

// Global halo (between blocks): halo[(blk*WW + e)*2 + s]; s=0 -> producer row
// 510 (consumer r-2), s=1 -> row 511 (r-1). Entry e = value after column e-1
// (entry 0 = initial x). low32 = float bits, high32 = tag (e+1).
// LDS halo (between waves of one block): same 8B tag+value atoms in a
// 64-group ring per boundary; ring overwrite prevented by a consumer
// progress counter (margin 44 < ring 64), checked once per 4 groups.
//
// RESTRUCTURE RATIONALE (rounds 0-9): every variation of the global halo
// protocol (gating x3, RMW->relaxed, store coalescing, clock-heater,
// load batching) left the ~220 cy/col cadence unchanged. The cost is the
// STRUCTURE: 64 cross-XCD hops and per-group exposed waits on single-wave
// blocks. This version: 8 waves/block relay through LDS (ds-speed), only
// 7 global hops; serial length 4096+63*skew -> 4096+7*skew.

__device__ __forceinline__ unsigned long long halo_ld(unsigned long long* p) {
    return __hip_atomic_load(p, __ATOMIC_RELAXED, __HIP_MEMORY_SCOPE_AGENT);
}
__device__ __forceinline__ void halo_st(unsigned long long* p, unsigned long long v) {
    __hip_atomic_store(p, v, __ATOMIC_RELAXED, __HIP_MEMORY_SCOPE_AGENT);
}
__device__ __forceinline__ unsigned long long lds_ld(const unsigned long long* p) {
    return __hip_atomic_load(p, __ATOMIC_RELAXED, __HIP_MEMORY_SCOPE_WORKGROUP);
}
__device__ __forceinline__ void lds_st(unsigned long long* p, unsigned long long v) {
    __hip_atomic_store(p, v, __ATOMIC_RELAXED, __HIP_MEMORY_SCOPE_WORKGROUP);
}
__device__ __forceinline__ unsigned prog_ld(const unsigned* p) {
    return __hip_atomic_load(p, __ATOMIC_RELAXED, __HIP_MEMORY_SCOPE_WORKGROUP);
}
__device__ __forceinline__ void prog_st(unsigned* p, unsigned v) {
    __hip_atomic_store(p, v, __ATOMIC_RELAXED, __HIP_MEMORY_SCOPE_WORKGROUP);
}

__device__ __forceinline__ float f4c(const float4& v, int k) {
    return (k == 0) ? v.x : ((k == 1) ? v.y : ((k == 2) ? v.z : v.w));
}

// shift all 64 lanes down by 1 at VALU speed; lane 0 receives fill's value
// (fill is wave-uniform: produced by a broadcast shuffle).
__device__ __forceinline__ float wave_shr1(float src, float fill) {
    return __int_as_float(__builtin_amdgcn_update_dpp(
        __float_as_int(fill), __float_as_int(src), 0x138, 0xF, 0xF, false));
}

// HW sin: v_sin_f32 computes sin(2*pi*x). |z| <= 3 -> no range reduction.
__device__ __forceinline__ float fast_sin(float z) {
    return __builtin_amdgcn_sinf(z * 0.15915494309189535f);  // 1/(2*pi)
}

#define COLSTEP(M, K)                                                        \
    do {                                                                     \
        float am1 = wave_shr1(a, Hhi[M][K]);                                 \
        float am2 = wave_shr1(am1, Hlo[M][K]);                               \
        const float z = fmaf(am2, f4c(W2v[M][(K) >> 2], (K) & 3),            \
                        fmaf(am1, f4c(W1v[M][(K) >> 2], (K) & 3),            \
                        fmaf(a,   f4c(Wv[M][(K) >> 2],  (K) & 3),            \
                                  f4c(Bv[M][(K) >> 2],  (K) & 3))));         \
        a = fast_sin(z);                                                     \
        Pv[K] = a;                                                           \
    } while (0)

// pack 8 published values (2 boundary rows x 8 cols) into lanes 0..15.
#define PACKPV(PVOUT)                                                        \
    do {                                                                     \
        PVOUT = 0.0f;                                                        \
        _Pragma("unroll")                                                    \
        for (int k = 0; k < U; ++k) {                                        \
            float t = __shfl(Pv[k], 62 + (lane & 1));                        \
            if ((lane >> 1) == k) PVOUT = t;                                 \
        }                                                                    \
    } while (0)

// wave 7: batched global publish (verified round 6: 2 write transactions).
#define PUBG(JB)                                                             \
    do {                                                                     \
        float pv; PACKPV(pv);                                                \
        const int e = (JB) + 1 + (lane >> 1);                                \
        if (lane < 16 && e < WW) {                                           \
            unsigned long long v =                                           \
                ((unsigned long long)(unsigned)(e + 1) << 32) |              \
                (unsigned long long)__float_as_uint(pv);                     \
            halo_st(&hme[(size_t)e * 2 + (lane & 1)], v);                    \
        }                                                                    \
    } while (0)

// waves 0..6: batched LDS publish into ring boundary `ldsp`.
#define LDSPUB(JB)                                                           \
    do {                                                                     \
        float pv; PACKPV(pv);                                                \
        const int e = (JB) + 1 + (lane >> 1);                                \
        if (lane < 16 && e < WW) {                                           \
            unsigned long long v =                                           \
                ((unsigned long long)(unsigned)(e + 1) << 32) |              \
                (unsigned long long)__float_as_uint(pv);                     \
            lds_st(&ldsp[((e & RMASK) << 1) | (lane & 1)], v);               \
        }                                                                    \
    } while (0)

#define LOADW(M, J)                                                          \
    do {                                                                     \
        const int _j = (J);                                                  \
        Wv[M][0]  = *(const float4*)(wp  + _j);                              \
        Wv[M][1]  = *(const float4*)(wp  + _j + 4);                          \
        W1v[M][0] = *(const float4*)(wp1 + _j);                              \
        W1v[M][1] = *(const float4*)(wp1 + _j + 4);                          \
        W2v[M][0] = *(const float4*)(wp2 + _j);                              \
        W2v[M][1] = *(const float4*)(wp2 + _j + 4);                          \
        Bv[M][0]  = *(const float4*)(bp  + _j);                              \
        Bv[M][1]  = *(const float4*)(bp  + _j + 4);                          \
    } while (0)

// wave 0, blk>0: global unpack (verbatim round 6; raw prefetched 4 groups
// ahead in Hg[]; probe-first retry).
#define UNPACKG(GIDX, BUF, SLOT)                                             \
    do {                                                                     \
        const int _jn = (GIDX) * U;                                          \
        if (blk > 0) {                                                       \
            bool myok = (lane >= 16) ||                                      \
                ((unsigned)(Hg[SLOT] >> 32) ==                               \
                 (unsigned)(_jn + (lane >> 1) + 1));                         \
            if (__builtin_expect(!__all(myok), 0)) {                         \
                for (;;) {                                                   \
                    if (lane < 16)                                           \
                        Hg[SLOT] = halo_ld(&hsrc[(size_t)_jn * 2 + lane]);   \
                    myok = (lane >= 16) ||                                   \
                        ((unsigned)(Hg[SLOT] >> 32) ==                       \
                         (unsigned)(_jn + (lane >> 1) + 1));                 \
                    if (__all(myok)) break;                                  \
                    __builtin_amdgcn_s_sleep(2);                             \
                }                                                            \
            }                                                                \
            float _hv = __uint_as_float((unsigned)(Hg[SLOT] & 0xffffffffu)); \
            _Pragma("unroll")                                                \
            for (int k = 0; k < U; ++k) {                                    \
                Hlo[BUF][k] = __shfl(_hv, 2 * k);                            \
                Hhi[BUF][k] = __shfl(_hv, 2 * k + 1);                        \
            }                                                                \
        }                                                                    \
    } while (0)

// waves 1..7: LDS unpack of group GIDX from prefetched Lga; tag-check,
// probe-first retry; then rotate Lga<-Lgb and prefetch group GIDX+2.
#define LDSUNPACK(GIDX, BUF)                                                 \
    do {                                                                     \
        const int _jn = (GIDX) * U;                                          \
        const int _e  = _jn + (lane >> 1);                                   \
        unsigned long long* _p =                                             \
            &ldsb[((_e & RMASK) << 1) | (lane & 1)];                         \
        bool ok = (lane >= 16) ||                                            \
                  ((unsigned)(Lga >> 32) == (unsigned)(_e + 1));             \
        if (__builtin_expect(!__all(ok), 0)) {                               \
            for (;;) {                                                       \
                Lga = lds_ld(_p);                                            \
                ok = (lane >= 16) ||                                         \
                     ((unsigned)(Lga >> 32) == (unsigned)(_e + 1));          \
                if (__all(ok)) break;                                        \
                __builtin_amdgcn_s_sleep(1);                                 \
            }                                                                \
        }                                                                    \
        float _hv = __uint_as_float((unsigned)(Lga & 0xffffffffu));          \
        _Pragma("unroll")                                                    \
        for (int k = 0; k < U; ++k) {                                        \
            Hlo[BUF][k] = __shfl(_hv, 2 * k);                                \
            Hhi[BUF][k] = __shfl(_hv, 2 * k + 1);                            \
        }                                                                    \
        Lga = Lgb;                                                           \
        if ((GIDX) + 2 < NGR) {                                              \
            const int _e2 = ((GIDX) + 2) * U + (lane >> 1);                  \
            Lgb = lds_ld(&ldsb[((_e2 & RMASK) << 1) | (lane & 1)]);          \
        }                                                                    \
    } while (0)

#define GROUPBODY(S)                                                         \
    do {                                                                     \
        const int G  = m * 4 + (S);                                          \
        const int jb = G * U;                                                \
        if (G + 1 < NGR) {                                                   \
            if (wave == 0) { UNPACKG(G + 1, ((S) + 1) & 1, ((S) + 1) & 3); } \
            else          { LDSUNPACK(G + 1, ((S) + 1) & 1); }               \
        }                                                                    \
        _Pragma("unroll")                                                    \
        for (int k = 0; k < U; ++k) COLSTEP((S) & 1, k);                     \
        if (wave == 7) { PUBG(jb); } else { LDSPUB(jb); }                    \
        const int jw = jb + 2 * U;                                           \
        if (jw < WW) LOADW((S) & 1, jw);                                     \
        if (wave == 0) {                                                     \
            const int jh = jb + 4 * U;                                       \
            if (jh < WW && blk > 0 && lane < 16)                             \
                Hg[S] = halo_ld(&hsrc[(size_t)jh * 2 + lane]);               \
        }                                                                    \
    } while (0)

__global__ __launch_bounds__(BT, 2) void neural_grid_scan(
    const float* __restrict__ x, const float* __restrict__ w,
    const float* __restrict__ bb, float* __restrict__ out,
    unsigned long long* __restrict__ halo)
{
    const int tid  = threadIdx.x;
    const int lane = tid & 63;
    const int wave = tid >> 6;
    const int blk  = blockIdx.x;
    const int row  = blk * BT + tid;
    const int r1 = (row >= 1) ? row - 1 : 0;   // am1==0 there, value unused
    const int r2 = (row >= 2) ? row - 2 : 0;

    const float* wp  = w  + (size_t)row * WW;
    const float* wp1 = w  + (size_t)r1  * WW;
    const float* wp2 = w  + (size_t)r2  * WW;
    const float* bp  = bb + (size_t)row * WW;

    unsigned long long* hme  = halo + (size_t)blk * WW * 2;
    unsigned long long* hsrc = halo + (size_t)(blk - 1) * WW * 2;

    __shared__ unsigned long long lds_h[7][RING_E * 2];   // 57344 B
    __shared__ unsigned int lds_prog[8];

    unsigned long long* ldsb = (wave > 0) ? &lds_h[wave - 1][0] : &lds_h[0][0];
    unsigned long long* ldsp = (wave < 7) ? &lds_h[wave][0]     : &lds_h[0][0];

    // zero ring tags + progress counters; one barrier before any publish.
    {
        unsigned long long* f = &lds_h[0][0];
        for (int i = tid; i < 7 * RING_E * 2; i += BT) f[i] = 0;
        if (tid < 8) lds_prog[tid] = 0;
    }
    __syncthreads();

    float a = x[row];

    // publish initial state (column -1 == x) into entry 0, tag 1.
    if (lane >= 62) {
        unsigned long long v =
            (1ULL << 32) | (unsigned long long)__float_as_uint(a);
        if (wave < 7) lds_st(&ldsp[lane - 62], v);
        else          halo_st(&hme[lane - 62], v);
    }

    // start gates (keep steady state out of the stall regime).
    if (wave == 0) {
        if (blk > 0 && lane == 0) {
            while ((unsigned)(halo_ld(&hsrc[(size_t)GATE * 2]) >> 32)
                   != (unsigned)(GATE + 1)) {
                __builtin_amdgcn_s_sleep(8);
            }
        }
    } else if (lane == 0) {
        while ((unsigned)(lds_ld(&ldsb[(LGATE & RMASK) << 1]) >> 32)
               != (unsigned)(LGATE + 1)) {
            __builtin_amdgcn_s_sleep(2);
        }
    }

    float4 Wv[2][2], W1v[2][2], W2v[2][2], Bv[2][2];
    unsigned long long Hg[4];
    unsigned long long Lga = 0, Lgb = 0;
    float Hlo[2][U] = {}, Hhi[2][U] = {};
    float Pv[U];

    LOADW(0, 0);
    LOADW(1, U);
    if (wave == 0) {
        if (blk > 0 && lane < 16) {
            Hg[0] = halo_ld(&hsrc[(size_t)(0 * U) * 2 + lane]);
            Hg[1] = halo_ld(&hsrc[(size_t)(1 * U) * 2 + lane]);
            Hg[2] = halo_ld(&hsrc[(size_t)(2 * U) * 2 + lane]);
            Hg[3] = halo_ld(&hsrc[(size_t)(3 * U) * 2 + lane]);
        } else {
            Hg[0] = Hg[1] = Hg[2] = Hg[3] = 0;
        }
        UNPACKG(0, 0, 0);
    } else {
        Hg[0] = Hg[1] = Hg[2] = Hg[3] = 0;
        {
            const int e0 = 0 * U + (lane >> 1);
            const int e1 = 1 * U + (lane >> 1);
            Lga = lds_ld(&ldsb[((e0 & RMASK) << 1) | (lane & 1)]);
            Lgb = lds_ld(&ldsb[((e1 & RMASK) << 1) | (lane & 1)]);
        }
        LDSUNPACK(0, 0);
    }

    for (int m = 0; m < NGR / 4; ++m) {
        // consumer progress (waves 1..7) and publisher throttle (waves 0..6):
        // ring depth 64 groups, margin 44 + <=4 batch + <=4 staleness < 64.
        if (wave > 0 && lane == 0) prog_st(&lds_prog[wave], (unsigned)(4 * m));
        if (wave < 7) {
            unsigned gp = 0;
            if (lane == 0) gp = prog_ld(&lds_prog[wave + 1]);
            gp = (unsigned)__shfl((int)gp, 0);
            while ((unsigned)(4 * m) > gp + 44u) {
                __builtin_amdgcn_s_sleep(2);
                if (lane == 0) gp = prog_ld(&lds_prog[wave + 1]);
                gp = (unsigned)__shfl((int)gp, 0);
            }
        }
        GROUPBODY(0);
        GROUPBODY(1);
        GROUPBODY(2);
        GROUPBODY(3);
    }

    out[row] = a;
}

extern "C" void kernel_launch(void* const* d_in, const int* in_sizes, int n_in,
                              void* d_out, int out_size, void* d_ws, size_t ws_size,
                              hipStream_t stream) {
    const float* x = (const float*)d_in[0];
    const float* w = (const float*)d_in[1];
    const float* b = (const float*)d_in[2];
    float* out = (float*)d_out;
    unsigned long long* halo = (unsigned long long*)d_ws;
    neural_grid_scan<<<dim3(NB), dim3(BT), 0, stream>>>(x, w, b, out, halo);
}